// Round 5
// baseline (159.739 us; speedup 1.0000x reference)
//
#include <hip/hip_runtime.h>
#include <hip/hip_bf16.h>
#include <math.h>

#define XDIM 2048
#define OW   2033        // 2048 - 16 + 1
#define TR   32          // out rows per block tile
#define TC   256         // out cols per block tile (64 per wave)
#define WPC  80          // pair-cols per wave slice (64 + 16 halo)
#define NROW 47          // i' rows per channel
#define NG   188         // 4 channels * 47 rows (divisible by 4)

typedef __bf16 bf16x8 __attribute__((ext_vector_type(8)));
typedef float  f32x16 __attribute__((ext_vector_type(16)));

union U128 { uint4 u; bf16x8 v; };

__device__ __forceinline__ unsigned short bfbits(float f) {
    return __builtin_bit_cast(unsigned short, __float2bfloat16(f));
}
// pair word: low16 = bf16(x^2) (plane p=0, weight w), high16 = bf16(x) (plane p=1, weight -2wk)
__device__ __forceinline__ unsigned int packx(float f) {
    return ((unsigned int)bfbits(f) << 16) | (unsigned int)bfbits(f * f);
}

__global__ __launch_bounds__(256) void psnr_mfma_kernel(
    const float* __restrict__ x,
    const float* __restrict__ kern,
    float* __restrict__ out)
{
    // Per-wave private ring: 8 rows x 80 overlapped pairs T[c]=(P[c],P[c+1]).
    // Each row written once, read once by its own wave -> ZERO block barriers
    // in steady state.
    __shared__ __align__(16) uint2 ring[4][8][WPC];           // 20.5 KB
    __shared__ __align__(16) unsigned int wt[4][17][20];      // 5.44 KB
    __shared__ float skkArr[4];

    const int tid  = threadIdx.x;
    const int lane = tid & 63;
    const int wv   = tid >> 6;         // wave 0..3
    const int nn   = lane & 31;        // m for A-frags, n for B-frags
    const int hf   = lane >> 5;        // k-block half

    const int r0  = blockIdx.y * TR;
    const int c0  = blockIdx.x * TC;
    const int c0w = c0 + (wv << 6);    // this wave's first out-col / x-col

    // ---- 4 named prefetch register sets (static indexing only) ----
    float4 s04, s14, s24, s34;
    float  s01, s11, s21, s31;

    auto issue = [&](int g, float4& v4, float& v1) {
        int ch = (g * 1395) >> 16;         // g/47 for g<256
        int ip = g - 47 * ch;
        if (lane < 20) {
            int gr = r0 + ip; if (gr > XDIM - 1) gr = XDIM - 1;
            int gc = c0w + 4 * lane;
            const float* rp = x + ((size_t)ch << 22) + (size_t)gr * XDIM;
            if (gc + 3 <= XDIM - 1) {
                v4 = *reinterpret_cast<const float4*>(rp + gc);
            } else {
                int e0 = gc     < XDIM ? gc     : XDIM - 1;
                int e1 = gc + 1 < XDIM ? gc + 1 : XDIM - 1;
                int e2 = gc + 2 < XDIM ? gc + 2 : XDIM - 1;
                int e3 = gc + 3 < XDIM ? gc + 3 : XDIM - 1;
                v4 = make_float4(rp[e0], rp[e1], rp[e2], rp[e3]);
            }
            int e4 = gc + 4 < XDIM ? gc + 4 : XDIM - 1;
            v1 = rp[e4];
        }
    };

    auto wr = [&](int g, const float4& v4, const float& v1) {
        if (lane < 20) {
            unsigned int P0 = packx(v4.x), P1 = packx(v4.y), P2 = packx(v4.z),
                         P3 = packx(v4.w), P4 = packx(v1);
            uint4* dst = reinterpret_cast<uint4*>(&ring[wv][g & 7][lane * 4]);
            dst[0] = make_uint4(P0, P1, P1, P2);
            dst[1] = make_uint4(P2, P3, P3, P4);
        }
    };

    // ---- get first loads in flight under the weight-table init ----
    issue(0, s04, s01);
    issue(1, s14, s11);
    issue(2, s24, s21);
    issue(3, s34, s31);

    // ---------------- weight tables + Skk (once per block) ----------------
    {
        float k0 = kern[tid], k1 = kern[256 + tid], k2 = kern[512 + tid], k3 = kern[768 + tid];
        float a  = k3 * (1.0f / 255.0f);
        float om = 1.0f - a;
        float w  = om * om;
        int i = tid >> 4, j = tid & 15;
        unsigned int wlo = (unsigned int)bfbits(w);
        wt[0][i][j] = ((unsigned int)bfbits(-2.0f * w * k0) << 16) | wlo;
        wt[1][i][j] = ((unsigned int)bfbits(-2.0f * w * k1) << 16) | wlo;
        wt[2][i][j] = ((unsigned int)bfbits(-2.0f * w * k2) << 16) | wlo;
        wt[3][i][j] = ((unsigned int)bfbits(-2.0f * w * k3) << 16) | wlo;
        if (tid < 80) {                       // zero row 16 of each channel table
            int c = tid / 20, wd = tid % 20;
            wt[c][16][wd] = 0u;
        }
        float4* red = reinterpret_cast<float4*>(&ring[0][0][0]);   // scratch
        red[tid] = make_float4(w*k0*k0, w*k1*k1, w*k2*k2, w*k3*k3);
        __syncthreads();
        #pragma unroll
        for (int s = 128; s > 0; s >>= 1) {
            if (tid < s) {
                float4 o = red[tid + s], m = red[tid];
                m.x += o.x; m.y += o.y; m.z += o.z; m.w += o.w;
                red[tid] = m;
            }
            __syncthreads();
        }
        if (tid == 0) {
            float4 r0v = red[0];
            skkArr[0] = r0v.x; skkArr[1] = r0v.y; skkArr[2] = r0v.z; skkArr[3] = r0v.w;
        }
        __syncthreads();   // LAST block barrier: wt/skk visible, ring scratch done
    }

    f32x16 acc0, acc1, psum0, psum1;
    #pragma unroll
    for (int q = 0; q < 16; ++q) { psum0[q] = 0.0f; psum1[q] = 0.0f; }

    const int xb = nn + 4 * hf;    // wave-local B base (pair-col)

    auto compute = [&](int g) {
        int ch = (g * 1395) >> 16;
        int ip = g - 47 * ch;
        if (ip == 0) {
            #pragma unroll
            for (int q = 0; q < 16; ++q) { acc0[q] = 0.0f; acc1[q] = 0.0f; }
        }
        const unsigned int* __restrict__ wch = &wt[ch][0][0];
        unsigned int d = (unsigned int)(ip - nn);
        unsigned int wrow = (d > 15u) ? 16u : d;
        U128 alo, ahi;
        alo.u = *reinterpret_cast<const uint4*>(wch + wrow * 20 + hf * 4);
        ahi.u = *reinterpret_cast<const uint4*>(wch + wrow * 20 + 8 + hf * 4);

        const uint2* __restrict__ bp = &ring[wv][g & 7][0];
        U128 blo0, bhi0, blo1, bhi1;
        { uint2 a0 = bp[xb],      a1 = bp[xb + 2];  blo0.u = make_uint4(a0.x, a0.y, a1.x, a1.y); }
        { uint2 a0 = bp[xb + 8],  a1 = bp[xb + 10]; bhi0.u = make_uint4(a0.x, a0.y, a1.x, a1.y); }
        { uint2 a0 = bp[xb + 32], a1 = bp[xb + 34]; blo1.u = make_uint4(a0.x, a0.y, a1.x, a1.y); }
        { uint2 a0 = bp[xb + 40], a1 = bp[xb + 42]; bhi1.u = make_uint4(a0.x, a0.y, a1.x, a1.y); }

        acc0 = __builtin_amdgcn_mfma_f32_32x32x16_bf16(alo.v, blo0.v, acc0, 0, 0, 0);
        acc0 = __builtin_amdgcn_mfma_f32_32x32x16_bf16(ahi.v, bhi0.v, acc0, 0, 0, 0);
        acc1 = __builtin_amdgcn_mfma_f32_32x32x16_bf16(alo.v, blo1.v, acc1, 0, 0, 0);
        acc1 = __builtin_amdgcn_mfma_f32_32x32x16_bf16(ahi.v, bhi1.v, acc1, 0, 0, 0);

        if (ip == NROW - 1) {              // channel epilogue
            float sk = skkArr[ch];
            #pragma unroll
            for (int q = 0; q < 16; ++q) {
                float m0 = (acc0[q] + sk) * (1.0f / 256.0f);
                float m1 = (acc1[q] + sk) * (1.0f / 256.0f);
                psum0[q] += log10f(m0);
                psum1[q] += log10f(m1);
            }
        }
    };

    // ---- prologue: row 0 staged; rows 1..4 in flight ----
    wr(0, s04, s01);
    issue(4, s04, s01);

    // ---- main loop: zero barriers, unrolled x4 so set choice is static ----
    for (int g = 0; g < NG; g += 4) {
        wr(g + 1, s14, s11);
        if (g + 5 < NG) issue(g + 5, s14, s11);
        compute(g);

        wr(g + 2, s24, s21);
        if (g + 6 < NG) issue(g + 6, s24, s21);
        compute(g + 1);

        wr(g + 3, s34, s31);
        if (g + 7 < NG) issue(g + 7, s34, s31);
        compute(g + 2);

        if (g + 4 < NG) { wr(g + 4, s04, s01); }
        if (g + 8 < NG) issue(g + 8, s04, s01);
        compute(g + 3);
    }

    // ---------------- store: psnr = 20log10(255) - 2.5 * sum_c log10(mse_c) ----------------
    const float BASE = 48.130803608679344f;
    const int col0 = c0w + nn;
    const int col1 = col0 + 32;
    #pragma unroll
    for (int q = 0; q < 16; ++q) {
        int row = r0 + (q & 3) + ((q >> 2) << 3) + (hf << 2);
        if (row < OW) {
            float* orow = out + (size_t)row * OW;
            if (col0 < OW) orow[col0] = BASE - 2.5f * psum0[q];
            if (col1 < OW) orow[col1] = BASE - 2.5f * psum1[q];
        }
    }
}

extern "C" void kernel_launch(void* const* d_in, const int* in_sizes, int n_in,
                              void* d_out, int out_size, void* d_ws, size_t ws_size,
                              hipStream_t stream) {
    (void)in_sizes; (void)n_in; (void)d_ws; (void)ws_size; (void)out_size;
    const float* x    = (const float*)d_in[0];
    const float* kern = (const float*)d_in[1];
    float* out        = (float*)d_out;

    dim3 grid(XDIM / TC, (OW + TR - 1) / TR);   // 8 x 64 = 512 blocks
    psnr_mfma_kernel<<<grid, 256, 0, stream>>>(x, kern, out);
}

// Round 6
// 95.312 us; speedup vs baseline: 1.6760x; 1.6760x over previous
//
#include <hip/hip_runtime.h>
#include <hip/hip_bf16.h>
#include <math.h>

#define XDIM 2048
#define OW   2033        // 2048 - 16 + 1
#define TR   32          // out rows per block tile
#define TC   256         // out cols per block tile
#define XW   272         // staged pair-words per image row (TC + 16)
#define NIT  13          // ceil(47*68 / 256) staging items per thread
#define NITEMS (47*68)   // 3196 float4 items per channel tile

typedef __bf16 bf16x8 __attribute__((ext_vector_type(8)));
typedef float  f32x16 __attribute__((ext_vector_type(16)));

union U128 { uint4 u; bf16x8 v; };

__device__ __forceinline__ unsigned short bfbits(float f) {
    return __builtin_bit_cast(unsigned short, __float2bfloat16(f));
}
// pair word: low16 = bf16(x^2) (plane p=0, weight w), high16 = bf16(x) (plane p=1, weight -2wk)
__device__ __forceinline__ unsigned int packx(float f) {
    return ((unsigned int)bfbits(f) << 16) | (unsigned int)bfbits(f * f);
}

__global__ __launch_bounds__(256) void psnr_mfma_kernel(
    const float* __restrict__ x,
    const float* __restrict__ kern,
    float* __restrict__ out)
{
    // Round-2 proven layout: whole-tile word-granular X~ (low conflicts), plus
    // one-channel-ahead register prefetch to hide staging latency under compute.
    __shared__ __align__(16) unsigned int xt[47 * XW];            // 51.1 KB
    __shared__ __align__(16) unsigned int wt[4][17][20];          // 5.44 KB
    __shared__ float skkArr[4];

    const int tid  = threadIdx.x;
    const int lane = tid & 63;
    const int wv   = tid >> 6;         // wave 0..3
    const int nn   = lane & 31;        // m for A-frags, n for B-frags
    const int hf   = lane >> 5;        // k-block half

    const int r0 = blockIdx.y * TR;
    const int c0 = blockIdx.x * TC;

    // ---- prefetch registers: fully-unrolled static indexing only ----
    float4 pf[NIT];

    auto issue = [&](int ch) {
        const float* __restrict__ xc = x + ((size_t)ch << 22);
        #pragma unroll
        for (int t = 0; t < NIT; ++t) {
            int idx = tid + 256 * t;
            if (idx < NITEMS) {
                int row = idx / 68;
                int q4  = (idx - row * 68) * 4;
                int gr  = r0 + row; if (gr > XDIM - 1) gr = XDIM - 1;
                int gc  = c0 + q4;
                const float* rp = xc + (size_t)gr * XDIM;
                if (gc + 3 <= XDIM - 1) {
                    pf[t] = *reinterpret_cast<const float4*>(rp + gc);
                } else {
                    int e0 = gc     < XDIM ? gc     : XDIM - 1;
                    int e1 = gc + 1 < XDIM ? gc + 1 : XDIM - 1;
                    int e2 = gc + 2 < XDIM ? gc + 2 : XDIM - 1;
                    int e3 = gc + 3 < XDIM ? gc + 3 : XDIM - 1;
                    pf[t] = make_float4(rp[e0], rp[e1], rp[e2], rp[e3]);
                }
            }
        }
    };

    auto wrt = [&]() {
        #pragma unroll
        for (int t = 0; t < NIT; ++t) {
            int idx = tid + 256 * t;
            if (idx < NITEMS) {
                int row = idx / 68;
                int q4  = (idx - row * 68) * 4;
                float4 v = pf[t];
                *reinterpret_cast<uint4*>(&xt[row * XW + q4]) =
                    make_uint4(packx(v.x), packx(v.y), packx(v.z), packx(v.w));
            }
        }
    };

    // ---- channel 0 loads in flight under the weight-table build ----
    issue(0);

    // ---------------- weight tables + Skk (once per block) ----------------
    {
        float k0 = kern[tid], k1 = kern[256 + tid], k2 = kern[512 + tid], k3 = kern[768 + tid];
        float a  = k3 * (1.0f / 255.0f);
        float om = 1.0f - a;
        float w  = om * om;
        int i = tid >> 4, j = tid & 15;
        unsigned int wlo = (unsigned int)bfbits(w);
        wt[0][i][j] = ((unsigned int)bfbits(-2.0f * w * k0) << 16) | wlo;
        wt[1][i][j] = ((unsigned int)bfbits(-2.0f * w * k1) << 16) | wlo;
        wt[2][i][j] = ((unsigned int)bfbits(-2.0f * w * k2) << 16) | wlo;
        wt[3][i][j] = ((unsigned int)bfbits(-2.0f * w * k3) << 16) | wlo;
        if (tid < 80) {                       // zero row 16 of each channel table
            int c = tid / 20, wd = tid % 20;
            wt[c][16][wd] = 0u;
        }
        float4* red = reinterpret_cast<float4*>(&xt[0]);   // 4KB scratch before staging
        red[tid] = make_float4(w*k0*k0, w*k1*k1, w*k2*k2, w*k3*k3);
        __syncthreads();
        #pragma unroll
        for (int s = 128; s > 0; s >>= 1) {
            if (tid < s) {
                float4 o = red[tid + s], m = red[tid];
                m.x += o.x; m.y += o.y; m.z += o.z; m.w += o.w;
                red[tid] = m;
            }
            __syncthreads();
        }
        if (tid == 0) {
            float4 r0v = red[0];
            skkArr[0] = r0v.x; skkArr[1] = r0v.y; skkArr[2] = r0v.z; skkArr[3] = r0v.w;
        }
        __syncthreads();   // wt/skk visible; xt scratch done
    }

    f32x16 psum0, psum1;
    #pragma unroll
    for (int q = 0; q < 16; ++q) { psum0[q] = 0.0f; psum1[q] = 0.0f; }

    const int xbase = nn + 4 * hf + (wv << 6);

    for (int ch = 0; ch < 4; ++ch) {
        // pack prefetched channel into LDS (no memory wait except vmcnt on pf)
        wrt();
        __syncthreads();
        // launch next channel's loads; they fly under the compute below
        if (ch < 3) issue(ch + 1);

        f32x16 acc0, acc1;
        #pragma unroll
        for (int q = 0; q < 16; ++q) { acc0[q] = 0.0f; acc1[q] = 0.0f; }

        const unsigned int* __restrict__ wch = &wt[ch][0][0];

        for (int ip = 0; ip < 47; ++ip) {
            unsigned int d = (unsigned int)(ip - nn);
            unsigned int wrow = (d > 15u) ? 16u : d;
            U128 alo, ahi;
            alo.u = *reinterpret_cast<const uint4*>(wch + wrow * 20 + hf * 4);
            ahi.u = *reinterpret_cast<const uint4*>(wch + wrow * 20 + 8 + hf * 4);

            int xb = ip * XW + xbase;
            U128 blo0, bhi0, blo1, bhi1;
            blo0.u = make_uint4(xt[xb],      xt[xb + 1],  xt[xb + 2],  xt[xb + 3]);
            bhi0.u = make_uint4(xt[xb + 8],  xt[xb + 9],  xt[xb + 10], xt[xb + 11]);
            blo1.u = make_uint4(xt[xb + 32], xt[xb + 33], xt[xb + 34], xt[xb + 35]);
            bhi1.u = make_uint4(xt[xb + 40], xt[xb + 41], xt[xb + 42], xt[xb + 43]);

            acc0 = __builtin_amdgcn_mfma_f32_32x32x16_bf16(alo.v, blo0.v, acc0, 0, 0, 0);
            acc0 = __builtin_amdgcn_mfma_f32_32x32x16_bf16(ahi.v, bhi0.v, acc0, 0, 0, 0);
            acc1 = __builtin_amdgcn_mfma_f32_32x32x16_bf16(alo.v, blo1.v, acc1, 0, 0, 0);
            acc1 = __builtin_amdgcn_mfma_f32_32x32x16_bf16(ahi.v, bhi1.v, acc1, 0, 0, 0);
        }

        // channel epilogue: fast log2 (v_log_f32), convert at the end
        float sk = skkArr[ch];
        #pragma unroll
        for (int q = 0; q < 16; ++q) {
            float m0 = (acc0[q] + sk) * (1.0f / 256.0f);
            float m1 = (acc1[q] + sk) * (1.0f / 256.0f);
            psum0[q] += __log2f(m0);
            psum1[q] += __log2f(m1);
        }

        __syncthreads();   // all waves done reading xt before next wrt
    }

    // psnr = 20log10(255) - 2.5 * sum_c log10(mse_c);  log10 = log2 * 0.30103
    const float BASE = 48.130803608679344f;
    const float SC   = 2.5f * 0.3010299956639812f;
    const int col0 = c0 + (wv << 6) + nn;
    const int col1 = col0 + 32;
    #pragma unroll
    for (int q = 0; q < 16; ++q) {
        int row = r0 + (q & 3) + ((q >> 2) << 3) + (hf << 2);
        if (row < OW) {
            float* orow = out + (size_t)row * OW;
            if (col0 < OW) orow[col0] = BASE - SC * psum0[q];
            if (col1 < OW) orow[col1] = BASE - SC * psum1[q];
        }
    }
}

extern "C" void kernel_launch(void* const* d_in, const int* in_sizes, int n_in,
                              void* d_out, int out_size, void* d_ws, size_t ws_size,
                              hipStream_t stream) {
    (void)in_sizes; (void)n_in; (void)d_ws; (void)ws_size; (void)out_size;
    const float* x    = (const float*)d_in[0];
    const float* kern = (const float*)d_in[1];
    float* out        = (float*)d_out;

    dim3 grid(XDIM / TC, (OW + TR - 1) / TR);   // 8 x 64 = 512 blocks
    psnr_mfma_kernel<<<grid, 256, 0, stream>>>(x, kern, out);
}